// Round 1
// baseline (256.619 us; speedup 1.0000x reference)
//
#include <hip/hip_runtime.h>

#define BATCH 4
#define SEQ   1024
#define EMB   256
#define NH    12
#define EH    3072   // EMB*NH
#define MROWS 4096   // BATCH*SEQ

typedef __attribute__((ext_vector_type(8))) short bf16x8;
typedef __attribute__((ext_vector_type(4))) float f32x4;
typedef __attribute__((ext_vector_type(4))) short short4v;

__device__ __forceinline__ short f2bf(float f) {
  union { float f; unsigned u; } x; x.f = f;
  unsigned r = x.u + 0x7fffu + ((x.u >> 16) & 1u);  // round-to-nearest-even
  return (short)(r >> 16);
}

__device__ __forceinline__ void gload_lds16(const void* g, void* l) {
  __builtin_amdgcn_global_load_lds(
      (const __attribute__((address_space(1))) unsigned*)g,
      (__attribute__((address_space(3))) unsigned*)l, 16, 0, 0);
}

// ---------------- cast x (fp32 -> bf16) ----------------
__global__ __launch_bounds__(256) void cast_x_kernel(const float* __restrict__ in,
                                                     short* __restrict__ out) {
  int i = (blockIdx.x * 256 + threadIdx.x) * 4;
  float4 v = *(const float4*)(in + i);
  short4v o;
  o[0] = f2bf(v.x); o[1] = f2bf(v.y); o[2] = f2bf(v.z); o[3] = f2bf(v.w);
  *(short4v*)(out + i) = o;
}

// ---------------- transpose + cast W[K][N] -> Wt[N][K] bf16 ----------------
__global__ __launch_bounds__(256) void transpose_cast_kernel(const float* __restrict__ W,
                                                             short* __restrict__ Wt,
                                                             int K, int N) {
  __shared__ float tile[32][33];
  const int n0 = blockIdx.x * 32, k0 = blockIdx.y * 32;
  const int tx = threadIdx.x & 31, ty = threadIdx.x >> 5;  // 32 x 8
#pragma unroll
  for (int i = 0; i < 4; i++)
    tile[ty + 8 * i][tx] = W[(size_t)(k0 + ty + 8 * i) * N + n0 + tx];
  __syncthreads();
#pragma unroll
  for (int i = 0; i < 4; i++) {
    int nr = ty + 8 * i;
    Wt[(size_t)(n0 + nr) * K + k0 + tx] = f2bf(tile[tx][nr]);
  }
}

// ---------------- GEMM: C[M][N] = A[M][K] * Bt[N][K]^T + bias ----------------
// EPI 0: bf16 C row-major. EPI 1: bf16 V transposed to [b][h][d][s]. EPI 2: fp32 C.
template <int BM, int BN, int EPI>
__global__ __launch_bounds__(256) void gemm_kernel(const short* __restrict__ A,
                                                   const short* __restrict__ Bt,
                                                   const float* __restrict__ bias,
                                                   void* __restrict__ Cout,
                                                   int M, int N, int K) {
  constexpr int BK = 32;
  constexpr int WM = BM / 2, WN = BN / 2;
  constexpr int MT = WM / 16, NT = WN / 16;
  __shared__ short As[BM * BK];
  __shared__ short Bs[BN * BK];
  const int tid = threadIdx.x;
  const int w = tid >> 6, lane = tid & 63;
  const int wm = w >> 1, wn = w & 1;
  const int l15 = lane & 15, l4 = lane >> 4;
  const int m0 = blockIdx.x * BM, n0 = blockIdx.y * BN;

  f32x4 acc[MT][NT] = {};

  constexpr int ACH = (BM * BK * 2) / 1024;  // 1KB chunks (16 rows x 64B)
  constexpr int BCH = (BN * BK * 2) / 1024;
  const int crow = lane >> 2;          // row within chunk
  const int ckb  = (lane & 3) * 16;    // byte within row

  for (int k0 = 0; k0 < K; k0 += BK) {
#pragma unroll
    for (int i = 0; i < ACH / 4; i++) {
      int c = w + i * 4;
      const char* src = (const char*)(A + (size_t)(m0 + c * 16 + crow) * K + k0) + ckb;
      gload_lds16(src, (char*)As + c * 1024);
    }
#pragma unroll
    for (int i = 0; i < BCH / 4; i++) {
      int c = w + i * 4;
      const char* src = (const char*)(Bt + (size_t)(n0 + c * 16 + crow) * K + k0) + ckb;
      gload_lds16(src, (char*)Bs + c * 1024);
    }
    asm volatile("s_waitcnt vmcnt(0)" ::: "memory");
    __syncthreads();

    bf16x8 af[MT], bfr[NT];
#pragma unroll
    for (int mt = 0; mt < MT; mt++)
      af[mt] = *(const bf16x8*)&As[(wm * WM + mt * 16 + l15) * BK + 8 * l4];
#pragma unroll
    for (int nt = 0; nt < NT; nt++)
      bfr[nt] = *(const bf16x8*)&Bs[(wn * WN + nt * 16 + l15) * BK + 8 * l4];
#pragma unroll
    for (int mt = 0; mt < MT; mt++)
#pragma unroll
      for (int nt = 0; nt < NT; nt++)
        acc[mt][nt] = __builtin_amdgcn_mfma_f32_16x16x32_bf16(af[mt], bfr[nt], acc[mt][nt], 0, 0, 0);
    __syncthreads();
  }

#pragma unroll
  for (int nt = 0; nt < NT; nt++) {
    const int n = n0 + wn * WN + nt * 16 + l15;
    const float bv = bias[n];
#pragma unroll
    for (int mt = 0; mt < MT; mt++) {
      const int mrow = m0 + wm * WM + mt * 16 + 4 * l4;
      f32x4 v = acc[mt][nt];
      if (EPI == 0) {
        short* C = (short*)Cout;
#pragma unroll
        for (int r = 0; r < 4; r++)
          C[(size_t)(mrow + r) * N + n] = f2bf(v[r] + bv);
      } else if (EPI == 1) {
        short* C = (short*)Cout;
        const int bb = mrow >> 10;       // SEQ = 1024
        const int s  = mrow & 1023;
        const int h  = n >> 8, d = n & 255;
        short4v o4;
        o4[0] = f2bf(v[0] + bv); o4[1] = f2bf(v[1] + bv);
        o4[2] = f2bf(v[2] + bv); o4[3] = f2bf(v[3] + bv);
        *(short4v*)&C[((size_t)(bb * NH + h) * EMB + d) * SEQ + s] = o4;
      } else {
        float* C = (float*)Cout;
#pragma unroll
        for (int r = 0; r < 4; r++)
          C[(size_t)(mrow + r) * N + n] = v[r] + bv;
      }
    }
  }
}

// ---------------- causal flash attention ----------------
// grid: (SEQ/64, BATCH*NH); block 256 (4 waves x 16 q-rows). KVBLK = 64.
__global__ __launch_bounds__(256) void attn_kernel(const short* __restrict__ Q,
                                                   const short* __restrict__ Kg,
                                                   const short* __restrict__ Vt,
                                                   short* __restrict__ Ctx) {
  __shared__ short Ks[64 * 256];   // [kv][d], rows swizzled
  __shared__ short Vs[256 * 64];   // [d][kv], rows swizzled
  __shared__ short Ps[4 * 16 * 64];// per-wave P tile [q][kv], swizzled
  const int tid = threadIdx.x, w = tid >> 6, lane = tid & 63;
  const int l15 = lane & 15, l4 = lane >> 4;
  const int bh = blockIdx.y, b = bh / NH, h = bh % NH;
  const int q0 = blockIdx.x * 64;

  // Q fragments in registers: 16 rows x 256 d per wave
  bf16x8 qf[8];
  {
    const short* qp = Q + (size_t)(b * SEQ + q0 + w * 16 + l15) * EH + h * EMB + 8 * l4;
#pragma unroll
    for (int kst = 0; kst < 8; kst++) qf[kst] = *(const bf16x8*)(qp + 32 * kst);
  }

  f32x4 o[16] = {};
  float mstate[4], lstate[4];
#pragma unroll
  for (int r = 0; r < 4; r++) { mstate[r] = -1e30f; lstate[r] = 0.f; }

  const int ntiles = q0 / 64 + 1;
  for (int t = 0; t < ntiles; t++) {
    const int kv0 = t * 64;
    // ---- stage K (64x256) and V^T (256x64) into LDS, swizzled ----
#pragma unroll
    for (int it = 0; it < 8; it++) {
      int c = it * 256 + tid;
      int row = c >> 5, e = (c & 31) * 8;          // K: 32 chunks per 512B row
      bf16x8 k8 = *(const bf16x8*)(Kg + (size_t)(b * SEQ + kv0 + row) * EH + h * EMB + e);
      *(bf16x8*)&Ks[row * 256 + (e ^ ((row & 7) << 3))] = k8;
      int row2 = c >> 3, e2 = (c & 7) * 8;         // V: 8 chunks per 128B row
      bf16x8 v8 = *(const bf16x8*)(Vt + (size_t)(bh * EMB + row2) * SEQ + kv0 + e2);
      *(bf16x8*)&Vs[row2 * 64 + (e2 ^ ((row2 & 7) << 3))] = v8;
    }
    __syncthreads();

    // ---- S = Q K^T ----
    f32x4 sf[4] = {};
#pragma unroll
    for (int nt = 0; nt < 4; nt++) {
      const int krow = nt * 16 + l15;
#pragma unroll
      for (int kst = 0; kst < 8; kst++) {
        bf16x8 kf = *(const bf16x8*)&Ks[krow * 256 + ((kst * 32 + 8 * l4) ^ ((krow & 7) << 3))];
        sf[nt] = __builtin_amdgcn_mfma_f32_16x16x32_bf16(qf[kst], kf, sf[nt], 0, 0, 0);
      }
    }

    // ---- online softmax (rows live in 16-lane groups) ----
    float pp[4][4];
    float fsc[4];
#pragma unroll
    for (int r = 0; r < 4; r++) {
      const int qrow = q0 + w * 16 + 4 * l4 + r;
      float sc[4];
      float mx = -1e30f;
#pragma unroll
      for (int nt = 0; nt < 4; nt++) {
        int kvg = kv0 + nt * 16 + l15;
        float s = sf[nt][r] * 0.0625f + (kvg > qrow ? -10000.0f : 0.0f);
        sc[nt] = s;
        mx = fmaxf(mx, s);
      }
      mx = fmaxf(mx, __shfl_xor(mx, 1));
      mx = fmaxf(mx, __shfl_xor(mx, 2));
      mx = fmaxf(mx, __shfl_xor(mx, 4));
      mx = fmaxf(mx, __shfl_xor(mx, 8));
      float mnew = fmaxf(mstate[r], mx);
      float f = __expf(mstate[r] - mnew);
      mstate[r] = mnew;
      float rs = 0.f;
#pragma unroll
      for (int nt = 0; nt < 4; nt++) {
        float e = __expf(sc[nt] - mnew);
        pp[nt][r] = e;
        rs += e;
      }
      rs += __shfl_xor(rs, 1);
      rs += __shfl_xor(rs, 2);
      rs += __shfl_xor(rs, 4);
      rs += __shfl_xor(rs, 8);
      lstate[r] = lstate[r] * f + rs;
      fsc[r] = f;
    }
#pragma unroll
    for (int nt = 0; nt < 16; nt++) {
      o[nt][0] *= fsc[0]; o[nt][1] *= fsc[1];
      o[nt][2] *= fsc[2]; o[nt][3] *= fsc[3];
    }

    // ---- P -> LDS (bf16, A-fragment layout source) ----
#pragma unroll
    for (int nt = 0; nt < 4; nt++)
#pragma unroll
      for (int r = 0; r < 4; r++) {
        int prow = 4 * l4 + r;
        Ps[w * 1024 + prow * 64 + ((l15 + 16 * nt) ^ ((prow & 7) << 3))] = f2bf(pp[nt][r]);
      }
    __syncthreads();

    // ---- O += P V ----
#pragma unroll
    for (int kst = 0; kst < 2; kst++) {
      bf16x8 af = *(const bf16x8*)&Ps[w * 1024 + l15 * 64 + ((kst * 32 + 8 * l4) ^ ((l15 & 7) << 3))];
#pragma unroll
      for (int nt = 0; nt < 16; nt++) {
        const int vrow = nt * 16 + l15;
        bf16x8 vf = *(const bf16x8*)&Vs[vrow * 64 + ((kst * 32 + 8 * l4) ^ ((vrow & 7) << 3))];
        o[nt] = __builtin_amdgcn_mfma_f32_16x16x32_bf16(af, vf, o[nt], 0, 0, 0);
      }
    }
    __syncthreads();
  }

  // ---- normalize + store ctx (bf16, merged layout [m][h*256+d]) ----
  float inv[4];
#pragma unroll
  for (int r = 0; r < 4; r++) inv[r] = 1.f / lstate[r];
  const int mrow = b * SEQ + q0 + w * 16 + 4 * l4;
#pragma unroll
  for (int nt = 0; nt < 16; nt++) {
    const int d = h * EMB + nt * 16 + l15;
#pragma unroll
    for (int r = 0; r < 4; r++)
      Ctx[(size_t)(mrow + r) * EH + d] = f2bf(o[nt][r] * inv[r]);
  }
}

extern "C" void kernel_launch(void* const* d_in, const int* in_sizes, int n_in,
                              void* d_out, int out_size, void* d_ws, size_t ws_size,
                              hipStream_t stream) {
  const float* x   = (const float*)d_in[0];
  const float* Wq  = (const float*)d_in[2];
  const float* bq  = (const float*)d_in[3];
  const float* Wk  = (const float*)d_in[4];
  const float* bk  = (const float*)d_in[5];
  const float* Wv  = (const float*)d_in[6];
  const float* bv  = (const float*)d_in[7];
  const float* Wfc = (const float*)d_in[8];
  const float* bfc = (const float*)d_in[9];
  float* out = (float*)d_out;

  short* ws   = (short*)d_ws;
  short* xb   = ws;                  // 4096*256
  short* wqt  = xb + 1048576;        // 3072*256
  short* wkt  = wqt + 786432;
  short* wvt  = wkt + 786432;
  short* wfct = wvt + 786432;        // 256*3072
  short* q    = wfct + 786432;       // 4096*3072
  short* k    = q + 12582912;
  short* vt   = k + 12582912;        // [b][h][d][s]
  short* ctx  = vt + 12582912;       // 4096*3072

  cast_x_kernel<<<1024, 256, 0, stream>>>(x, xb);
  transpose_cast_kernel<<<dim3(EH / 32, EMB / 32), 256, 0, stream>>>(Wq, wqt, EMB, EH);
  transpose_cast_kernel<<<dim3(EH / 32, EMB / 32), 256, 0, stream>>>(Wk, wkt, EMB, EH);
  transpose_cast_kernel<<<dim3(EH / 32, EMB / 32), 256, 0, stream>>>(Wv, wvt, EMB, EH);
  transpose_cast_kernel<<<dim3(EMB / 32, EH / 32), 256, 0, stream>>>(Wfc, wfct, EH, EMB);

  gemm_kernel<128, 128, 0><<<dim3(MROWS / 128, EH / 128), 256, 0, stream>>>(xb, wqt, bq, q, MROWS, EH, EMB);
  gemm_kernel<128, 128, 0><<<dim3(MROWS / 128, EH / 128), 256, 0, stream>>>(xb, wkt, bk, k, MROWS, EH, EMB);
  gemm_kernel<128, 128, 1><<<dim3(MROWS / 128, EH / 128), 256, 0, stream>>>(xb, wvt, bv, vt, MROWS, EH, EMB);

  attn_kernel<<<dim3(SEQ / 64, BATCH * NH), 256, 0, stream>>>(q, k, vt, ctx);

  gemm_kernel<64, 64, 2><<<dim3(MROWS / 64, EMB / 64), 256, 0, stream>>>(ctx, wfct, bfc, out, MROWS, EMB, EH);
}

// Round 2
// 207.323 us; speedup vs baseline: 1.2378x; 1.2378x over previous
//
#include <hip/hip_runtime.h>

#define BATCH 4
#define SEQ   1024
#define EMB   256
#define NH    12
#define EH    3072   // EMB*NH
#define MROWS 4096   // BATCH*SEQ

typedef __attribute__((ext_vector_type(8))) short bf16x8;
typedef __attribute__((ext_vector_type(4))) float f32x4;
typedef __attribute__((ext_vector_type(4))) short short4v;

__device__ __forceinline__ short f2bf(float f) {
  union { float f; unsigned u; } x; x.f = f;
  unsigned r = x.u + 0x7fffu + ((x.u >> 16) & 1u);  // round-to-nearest-even
  return (short)(r >> 16);
}

__device__ __forceinline__ void gload_lds16(const void* g, void* l) {
  __builtin_amdgcn_global_load_lds(
      (const __attribute__((address_space(1))) unsigned*)g,
      (__attribute__((address_space(3))) unsigned*)l, 16, 0, 0);
}

// ---------------- cast x (fp32 -> bf16) ----------------
__global__ __launch_bounds__(256) void cast_x_kernel(const float* __restrict__ in,
                                                     short* __restrict__ out) {
  int i = (blockIdx.x * 256 + threadIdx.x) * 4;
  float4 v = *(const float4*)(in + i);
  short4v o;
  o[0] = f2bf(v.x); o[1] = f2bf(v.y); o[2] = f2bf(v.z); o[3] = f2bf(v.w);
  *(short4v*)(out + i) = o;
}

// ---------------- transpose + cast W[K][N] -> Wt[N][K] bf16 ----------------
__global__ __launch_bounds__(256) void transpose_cast_kernel(const float* __restrict__ W,
                                                             short* __restrict__ Wt,
                                                             int K, int N) {
  __shared__ float tile[32][33];
  const int n0 = blockIdx.x * 32, k0 = blockIdx.y * 32;
  const int tx = threadIdx.x & 31, ty = threadIdx.x >> 5;  // 32 x 8
#pragma unroll
  for (int i = 0; i < 4; i++)
    tile[ty + 8 * i][tx] = W[(size_t)(k0 + ty + 8 * i) * N + n0 + tx];
  __syncthreads();
#pragma unroll
  for (int i = 0; i < 4; i++) {
    int nr = ty + 8 * i;
    Wt[(size_t)(n0 + nr) * K + k0 + tx] = f2bf(tile[tx][nr]);
  }
}

// ---------------- GEMM: C[M][N] = A[M][K] * Bt[N][K]^T + bias ----------------
// EPI 0: bf16 C row-major. EPI 1: bf16 V transposed to [b][h][d][s]. EPI 2: fp32 C.
template <int BM, int BN, int EPI>
__global__ __launch_bounds__(256) void gemm_kernel(const short* __restrict__ A,
                                                   const short* __restrict__ Bt,
                                                   const float* __restrict__ bias,
                                                   void* __restrict__ Cout,
                                                   int M, int N, int K) {
  constexpr int BK = 32;
  constexpr int WM = BM / 2, WN = BN / 2;
  constexpr int MT = WM / 16, NT = WN / 16;
  __shared__ short As[BM * BK];
  __shared__ short Bs[BN * BK];
  const int tid = threadIdx.x;
  const int w = tid >> 6, lane = tid & 63;
  const int wm = w >> 1, wn = w & 1;
  const int l15 = lane & 15, l4 = lane >> 4;
  const int m0 = blockIdx.x * BM, n0 = blockIdx.y * BN;

  f32x4 acc[MT][NT] = {};

  constexpr int ACH = (BM * BK * 2) / 1024;  // 1KB chunks (16 rows x 64B)
  constexpr int BCH = (BN * BK * 2) / 1024;
  const int crow = lane >> 2;          // row within chunk
  const int ckb  = (lane & 3) * 16;    // byte within row

  for (int k0 = 0; k0 < K; k0 += BK) {
#pragma unroll
    for (int i = 0; i < ACH / 4; i++) {
      int c = w + i * 4;
      const char* src = (const char*)(A + (size_t)(m0 + c * 16 + crow) * K + k0) + ckb;
      gload_lds16(src, (char*)As + c * 1024);
    }
#pragma unroll
    for (int i = 0; i < BCH / 4; i++) {
      int c = w + i * 4;
      const char* src = (const char*)(Bt + (size_t)(n0 + c * 16 + crow) * K + k0) + ckb;
      gload_lds16(src, (char*)Bs + c * 1024);
    }
    asm volatile("s_waitcnt vmcnt(0)" ::: "memory");
    __syncthreads();

    bf16x8 af[MT], bfr[NT];
#pragma unroll
    for (int mt = 0; mt < MT; mt++)
      af[mt] = *(const bf16x8*)&As[(wm * WM + mt * 16 + l15) * BK + 8 * l4];
#pragma unroll
    for (int nt = 0; nt < NT; nt++)
      bfr[nt] = *(const bf16x8*)&Bs[(wn * WN + nt * 16 + l15) * BK + 8 * l4];
#pragma unroll
    for (int mt = 0; mt < MT; mt++)
#pragma unroll
      for (int nt = 0; nt < NT; nt++)
        acc[mt][nt] = __builtin_amdgcn_mfma_f32_16x16x32_bf16(af[mt], bfr[nt], acc[mt][nt], 0, 0, 0);
    __syncthreads();
  }

#pragma unroll
  for (int nt = 0; nt < NT; nt++) {
    const int n = n0 + wn * WN + nt * 16 + l15;
    const float bv = bias[n];
#pragma unroll
    for (int mt = 0; mt < MT; mt++) {
      const int mrow = m0 + wm * WM + mt * 16 + 4 * l4;
      f32x4 v = acc[mt][nt];
      if (EPI == 0) {
        short* C = (short*)Cout;
#pragma unroll
        for (int r = 0; r < 4; r++)
          C[(size_t)(mrow + r) * N + n] = f2bf(v[r] + bv);
      } else if (EPI == 1) {
        short* C = (short*)Cout;
        const int bb = mrow >> 10;       // SEQ = 1024
        const int s  = mrow & 1023;
        const int h  = n >> 8, d = n & 255;
        short4v o4;
        o4[0] = f2bf(v[0] + bv); o4[1] = f2bf(v[1] + bv);
        o4[2] = f2bf(v[2] + bv); o4[3] = f2bf(v[3] + bv);
        *(short4v*)&C[((size_t)(bb * NH + h) * EMB + d) * SEQ + s] = o4;
      } else {
        float* C = (float*)Cout;
#pragma unroll
        for (int r = 0; r < 4; r++)
          C[(size_t)(mrow + r) * N + n] = v[r] + bv;
      }
    }
  }
}

// ---------------- causal flash attention ----------------
// grid: (BATCH*NH, SEQ/64) with q-tile = 15 - blockIdx.y  => heaviest blocks
// dispatch first (48 of them), packing the causal-imbalanced schedule.
// block 256 (4 waves x 16 q-rows). KVBLK = 64.
// T14 async-STAGE: next tile's K/V loaded to regs during compute, written to
// LDS after the buffer-free barriers.
__global__ __launch_bounds__(256) void attn_kernel(const short* __restrict__ Q,
                                                   const short* __restrict__ Kg,
                                                   const short* __restrict__ Vt,
                                                   short* __restrict__ Ctx) {
  __shared__ short Ks[64 * 256];   // [kv][d], rows swizzled
  __shared__ short Vs[256 * 64];   // [d][kv], rows swizzled
  __shared__ short Ps[4 * 16 * 64];// per-wave P tile [q][kv], swizzled
  const int tid = threadIdx.x, w = tid >> 6, lane = tid & 63;
  const int l15 = lane & 15, l4 = lane >> 4;
  const int bh = blockIdx.x, b = bh / NH, h = bh % NH;
  const int qt = (gridDim.y - 1) - blockIdx.y;   // heavy-first
  const int q0 = qt * 64;
  const int ntiles = qt + 1;

  // per-thread staging geometry (same for reg-load and LDS-write)
  const int krow = tid >> 2, ke = (tid & 3) * 8;        // K: tid covers 1/8 of 64x256 per it
  const int vrow = tid >> 0;                            // V: row = (it*256+tid)>>3 -> use c
  // Q fragments in registers: 16 rows x 256 d per wave
  bf16x8 qf[8];
  {
    const short* qp = Q + (size_t)(b * SEQ + q0 + w * 16 + l15) * EH + h * EMB + 8 * l4;
#pragma unroll
    for (int kst = 0; kst < 8; kst++) qf[kst] = *(const bf16x8*)(qp + 32 * kst);
  }

  const short* Kbase = Kg + (size_t)b * SEQ * EH + h * EMB;
  const short* Vbase = Vt + (size_t)bh * EMB * SEQ;

  bf16x8 kreg[8], vreg[8];
  // ---- prologue: stage tile 0 ----
#pragma unroll
  for (int it = 0; it < 8; it++) {
    int c = it * 256 + tid;
    int row = c >> 5, e = (c & 31) * 8;
    kreg[it] = *(const bf16x8*)(Kbase + (size_t)row * EH + e);
    int row2 = c >> 3, e2 = (c & 7) * 8;
    vreg[it] = *(const bf16x8*)(Vbase + (size_t)row2 * SEQ + e2);
  }
#pragma unroll
  for (int it = 0; it < 8; it++) {
    int c = it * 256 + tid;
    int row = c >> 5, e = (c & 31) * 8;
    *(bf16x8*)&Ks[row * 256 + (e ^ ((row & 7) << 3))] = kreg[it];
    int row2 = c >> 3, e2 = (c & 7) * 8;
    *(bf16x8*)&Vs[row2 * 64 + (e2 ^ ((row2 & 7) << 3))] = vreg[it];
  }
  __syncthreads();

  f32x4 o[16] = {};
  float mstate[4], lstate[4];
#pragma unroll
  for (int r = 0; r < 4; r++) { mstate[r] = -1e30f; lstate[r] = 0.f; }

  for (int t = 0; t < ntiles; t++) {
    const int kv0 = t * 64;
    const bool pf = (t + 1 < ntiles);   // block-uniform

    // ---- issue next-tile K loads (latency hides under QK+softmax) ----
    if (pf) {
      const short* kp = Kbase + (size_t)(kv0 + 64) * EH;
#pragma unroll
      for (int it = 0; it < 8; it++) {
        int c = it * 256 + tid;
        int row = c >> 5, e = (c & 31) * 8;
        kreg[it] = *(const bf16x8*)(kp + (size_t)row * EH + e);
      }
    }

    // ---- S = Q K^T ----
    f32x4 sf[4] = {};
    __builtin_amdgcn_s_setprio(1);
#pragma unroll
    for (int nt = 0; nt < 4; nt++) {
      const int krw = nt * 16 + l15;
#pragma unroll
      for (int kst = 0; kst < 8; kst++) {
        bf16x8 kf = *(const bf16x8*)&Ks[krw * 256 + ((kst * 32 + 8 * l4) ^ ((krw & 7) << 3))];
        sf[nt] = __builtin_amdgcn_mfma_f32_16x16x32_bf16(qf[kst], kf, sf[nt], 0, 0, 0);
      }
    }
    __builtin_amdgcn_s_setprio(0);

    // ---- issue next-tile V loads (latency hides under softmax+PV) ----
    if (pf) {
#pragma unroll
      for (int it = 0; it < 8; it++) {
        int c = it * 256 + tid;
        int row2 = c >> 3, e2 = (c & 7) * 8;
        vreg[it] = *(const bf16x8*)(Vbase + (size_t)row2 * SEQ + kv0 + 64 + e2);
      }
    }

    // ---- online softmax (rows live in 16-lane groups) ----
    float pp[4][4];
    float fsc[4];
#pragma unroll
    for (int r = 0; r < 4; r++) {
      const int qrow = q0 + w * 16 + 4 * l4 + r;
      float sc[4];
      float mx = -1e30f;
#pragma unroll
      for (int nt = 0; nt < 4; nt++) {
        int kvg = kv0 + nt * 16 + l15;
        float s = sf[nt][r] * 0.0625f + (kvg > qrow ? -10000.0f : 0.0f);
        sc[nt] = s;
        mx = fmaxf(mx, s);
      }
      mx = fmaxf(mx, __shfl_xor(mx, 1));
      mx = fmaxf(mx, __shfl_xor(mx, 2));
      mx = fmaxf(mx, __shfl_xor(mx, 4));
      mx = fmaxf(mx, __shfl_xor(mx, 8));
      float mnew = fmaxf(mstate[r], mx);
      float f = __expf(mstate[r] - mnew);
      mstate[r] = mnew;
      float rs = 0.f;
#pragma unroll
      for (int nt = 0; nt < 4; nt++) {
        float e = __expf(sc[nt] - mnew);
        pp[nt][r] = e;
        rs += e;
      }
      rs += __shfl_xor(rs, 1);
      rs += __shfl_xor(rs, 2);
      rs += __shfl_xor(rs, 4);
      rs += __shfl_xor(rs, 8);
      lstate[r] = lstate[r] * f + rs;
      fsc[r] = f;
    }
#pragma unroll
    for (int nt = 0; nt < 16; nt++) {
      o[nt][0] *= fsc[0]; o[nt][1] *= fsc[1];
      o[nt][2] *= fsc[2]; o[nt][3] *= fsc[3];
    }

    // ---- P -> LDS (bf16, A-fragment layout source) ----
#pragma unroll
    for (int nt = 0; nt < 4; nt++)
#pragma unroll
      for (int r = 0; r < 4; r++) {
        int prow = 4 * l4 + r;
        Ps[w * 1024 + prow * 64 + ((l15 + 16 * nt) ^ ((prow & 7) << 3))] = f2bf(pp[nt][r]);
      }
    __syncthreads();   // D: Ks reads done (QK finished), Ps visible

    // ---- write next K tile into Ks (overlaps PV) ----
    if (pf) {
#pragma unroll
      for (int it = 0; it < 8; it++) {
        int c = it * 256 + tid;
        int row = c >> 5, e = (c & 31) * 8;
        *(bf16x8*)&Ks[row * 256 + (e ^ ((row & 7) << 3))] = kreg[it];
      }
    }

    // ---- O += P V ----
    __builtin_amdgcn_s_setprio(1);
#pragma unroll
    for (int kst = 0; kst < 2; kst++) {
      bf16x8 af = *(const bf16x8*)&Ps[w * 1024 + l15 * 64 + ((kst * 32 + 8 * l4) ^ ((l15 & 7) << 3))];
#pragma unroll
      for (int nt = 0; nt < 16; nt++) {
        const int vrw = nt * 16 + l15;
        bf16x8 vf = *(const bf16x8*)&Vs[vrw * 64 + ((kst * 32 + 8 * l4) ^ ((vrw & 7) << 3))];
        o[nt] = __builtin_amdgcn_mfma_f32_16x16x32_bf16(af, vf, o[nt], 0, 0, 0);
      }
    }
    __builtin_amdgcn_s_setprio(0);
    __syncthreads();   // F: Vs/Ps reads done

    // ---- write next V tile into Vs ----
    if (pf) {
#pragma unroll
      for (int it = 0; it < 8; it++) {
        int c = it * 256 + tid;
        int row2 = c >> 3, e2 = (c & 7) * 8;
        *(bf16x8*)&Vs[row2 * 64 + (e2 ^ ((row2 & 7) << 3))] = vreg[it];
      }
      __syncthreads(); // H: next tile staged
    }
  }

  // ---- normalize + store ctx (bf16, merged layout [m][h*256+d]) ----
  float inv[4];
#pragma unroll
  for (int r = 0; r < 4; r++) inv[r] = 1.f / lstate[r];
  const int mrow = b * SEQ + q0 + w * 16 + 4 * l4;
#pragma unroll
  for (int nt = 0; nt < 16; nt++) {
    const int d = h * EMB + nt * 16 + l15;
#pragma unroll
    for (int r = 0; r < 4; r++)
      Ctx[(size_t)(mrow + r) * EH + d] = f2bf(o[nt][r] * inv[r]);
  }
}

extern "C" void kernel_launch(void* const* d_in, const int* in_sizes, int n_in,
                              void* d_out, int out_size, void* d_ws, size_t ws_size,
                              hipStream_t stream) {
  const float* x   = (const float*)d_in[0];
  const float* Wq  = (const float*)d_in[2];
  const float* bq  = (const float*)d_in[3];
  const float* Wk  = (const float*)d_in[4];
  const float* bk  = (const float*)d_in[5];
  const float* Wv  = (const float*)d_in[6];
  const float* bv  = (const float*)d_in[7];
  const float* Wfc = (const float*)d_in[8];
  const float* bfc = (const float*)d_in[9];
  float* out = (float*)d_out;

  short* ws   = (short*)d_ws;
  short* xb   = ws;                  // 4096*256
  short* wqt  = xb + 1048576;        // 3072*256
  short* wkt  = wqt + 786432;
  short* wvt  = wkt + 786432;
  short* wfct = wvt + 786432;        // 256*3072
  short* q    = wfct + 786432;       // 4096*3072
  short* k    = q + 12582912;
  short* vt   = k + 12582912;        // [b][h][d][s]
  short* ctx  = vt + 12582912;       // 4096*3072

  cast_x_kernel<<<1024, 256, 0, stream>>>(x, xb);
  transpose_cast_kernel<<<dim3(EH / 32, EMB / 32), 256, 0, stream>>>(Wq, wqt, EMB, EH);
  transpose_cast_kernel<<<dim3(EH / 32, EMB / 32), 256, 0, stream>>>(Wk, wkt, EMB, EH);
  transpose_cast_kernel<<<dim3(EH / 32, EMB / 32), 256, 0, stream>>>(Wv, wvt, EMB, EH);
  transpose_cast_kernel<<<dim3(EMB / 32, EH / 32), 256, 0, stream>>>(Wfc, wfct, EH, EMB);

  gemm_kernel<128, 128, 0><<<dim3(MROWS / 128, EH / 128), 256, 0, stream>>>(xb, wqt, bq, q, MROWS, EH, EMB);
  gemm_kernel<128, 128, 0><<<dim3(MROWS / 128, EH / 128), 256, 0, stream>>>(xb, wkt, bk, k, MROWS, EH, EMB);
  gemm_kernel<128, 128, 1><<<dim3(MROWS / 128, EH / 128), 256, 0, stream>>>(xb, wvt, bv, vt, MROWS, EH, EMB);

  attn_kernel<<<dim3(BATCH * NH, SEQ / 64), 256, 0, stream>>>(q, k, vt, ctx);

  gemm_kernel<64, 64, 2><<<dim3(MROWS / 64, EMB / 64), 256, 0, stream>>>(ctx, wfct, bfc, out, MROWS, EMB, EH);
}